// Round 1
// baseline (347.030 us; speedup 1.0000x reference)
//
#include <hip/hip_runtime.h>
#include <cmath>

#define D 256
#define NH 8
#define B 2

// ---- ordered-uint mapping for float atomicMax ----
__device__ inline unsigned f2ord(float f) {
    unsigned u = __float_as_uint(f);
    return (u & 0x80000000u) ? ~u : (u | 0x80000000u);
}
__device__ inline float ord2f(unsigned u) {
    unsigned b = (u & 0x80000000u) ? (u & 0x7FFFFFFFu) : ~u;
    return __uint_as_float(b);
}

// K1: one wave (64 lanes) per edge. Each lane loads float4 from q-row and
// k-row (fully coalesced, 1KB per row per wave). 8 lanes per head; xor-shuffle
// reduce within 8-lane groups. Scores written to d_out as s[b][m][8].
__global__ __launch_bounds__(256) void k_scores(
    const float* __restrict__ q, const float* __restrict__ k,
    const int* __restrict__ e, float* __restrict__ s, int n, int m)
{
    int wave = (int)((blockIdx.x * blockDim.x + threadIdx.x) >> 6);
    int lane = threadIdx.x & 63;
    if (wave >= m) return;
    int j  = wave;
    int e0 = e[j];
    int e1 = e[m + j];

    #pragma unroll
    for (int bb = 0; bb < B; ++bb) {
        const float4* qr = (const float4*)(q + ((size_t)bb * n + e0) * D);
        const float4* kr = (const float4*)(k + ((size_t)bb * n + e1) * D);
        float4 a4 = qr[lane];
        float4 b4 = kr[lane];
        float p = a4.x * b4.x + a4.y * b4.y + a4.z * b4.z + a4.w * b4.w;
        // reduce across the 8 lanes of this head (lanes 8h..8h+7)
        p += __shfl_xor(p, 1);
        p += __shfl_xor(p, 2);
        p += __shfl_xor(p, 4);
        if ((lane & 7) == 0) {
            int h = lane >> 3;
            s[((size_t)bb * m + j) * NH + h] = p * 0.0625f; // / sqrt(256)
        }
    }
}

// K2: grid-stride max over all scores; one atomicMax per block.
__global__ __launch_bounds__(256) void k_max(
    const float* __restrict__ s, size_t total, unsigned* __restrict__ gmax)
{
    float mx = -INFINITY;
    for (size_t i = blockIdx.x * (size_t)blockDim.x + threadIdx.x; i < total;
         i += (size_t)gridDim.x * blockDim.x)
        mx = fmaxf(mx, s[i]);
    #pragma unroll
    for (int off = 32; off; off >>= 1)
        mx = fmaxf(mx, __shfl_xor(mx, off));
    __shared__ float sm[4];
    int lane = threadIdx.x & 63, w = threadIdx.x >> 6;
    if (lane == 0) sm[w] = mx;
    __syncthreads();
    if (threadIdx.x == 0) {
        float bm = fmaxf(fmaxf(sm[0], sm[1]), fmaxf(sm[2], sm[3]));
        atomicMax(gmax, f2ord(bm));
    }
}

// K3: ex = exp(s - M) in-place; atomicAdd into seg[r[j]][bb][h].
__global__ __launch_bounds__(256) void k_exp_seg(
    float* __restrict__ s, const int* __restrict__ r,
    const unsigned* __restrict__ gmax, float* __restrict__ seg, int m)
{
    float M = ord2f(*gmax);
    size_t total = (size_t)B * m * NH;
    for (size_t i = blockIdx.x * (size_t)blockDim.x + threadIdx.x; i < total;
         i += (size_t)gridDim.x * blockDim.x) {
        float ex = expf(s[i] - M);
        s[i] = ex;
        size_t bj = i >> 3;               // bb*m + j
        int h  = (int)(i & 7);
        int bb = (bj >= (size_t)m) ? 1 : 0;
        int j  = (int)(bj - (size_t)bb * m);
        atomicAdd(&seg[((size_t)r[j] * B + bb) * NH + h], ex);
    }
}

// K4: out = ex / (seg[r[j]][bb][h] + eps), in-place on d_out.
__global__ __launch_bounds__(256) void k_norm(
    float* __restrict__ s, const int* __restrict__ r,
    const float* __restrict__ seg, int m)
{
    size_t total = (size_t)B * m * NH;
    for (size_t i = blockIdx.x * (size_t)blockDim.x + threadIdx.x; i < total;
         i += (size_t)gridDim.x * blockDim.x) {
        size_t bj = i >> 3;
        int h  = (int)(i & 7);
        int bb = (bj >= (size_t)m) ? 1 : 0;
        int j  = (int)(bj - (size_t)bb * m);
        float denom = seg[((size_t)r[j] * B + bb) * NH + h] + 1e-16f;
        s[i] = s[i] / denom;
    }
}

extern "C" void kernel_launch(void* const* d_in, const int* in_sizes, int n_in,
                              void* d_out, int out_size, void* d_ws, size_t ws_size,
                              hipStream_t stream) {
    const float* q = (const float*)d_in[0];
    const float* k = (const float*)d_in[1];
    const int*   e = (const int*)d_in[2];
    const int*   r = (const int*)d_in[3];
    float* s = (float*)d_out;               // scores -> ex -> out, in place

    int n = in_sizes[0] / (B * D);          // 20000
    int m = in_sizes[3];                    // 320000

    unsigned* gmax = (unsigned*)d_ws;
    float*    seg  = (float*)((char*)d_ws + 16);
    size_t seg_bytes = (size_t)n * B * NH * sizeof(float);

    // zero max slot (ord 0 == very negative float) + seg accumulators
    hipMemsetAsync(d_ws, 0, 16 + seg_bytes, stream);

    size_t total = (size_t)B * m * NH;      // 5.12M

    // K1: m waves, 4 waves/block
    k_scores<<<(m + 3) / 4, 256, 0, stream>>>(q, k, e, s, n, m);
    // K2: global max
    k_max<<<1024, 256, 0, stream>>>(s, total, gmax);
    // K3: exp + segment sum
    k_exp_seg<<<4096, 256, 0, stream>>>(s, r, gmax, seg, m);
    // K4: normalize
    k_norm<<<4096, 256, 0, stream>>>(s, r, seg, m);
}

// Round 3
// 340.881 us; speedup vs baseline: 1.0180x; 1.0180x over previous
//
#include <hip/hip_runtime.h>
#include <cmath>

#define D 256
#define NH 8
#define B 2
#define EPW 4   // edges per wave

// ---- ordered-uint mapping for float atomicMax ----
__device__ inline unsigned f2ord(float f) {
    unsigned u = __float_as_uint(f);
    return (u & 0x80000000u) ? ~u : (u | 0x80000000u);
}
__device__ inline float ord2f(unsigned u) {
    unsigned b = (u & 0x80000000u) ? (u & 0x7FFFFFFFu) : ~u;
    return __uint_as_float(b);
}

// K1: one wave handles EPW edges. All 2*B*EPW float4 row-loads are issued
// back-to-back (independent -> in flight together) before any reduction.
// 8 lanes per head; xor-shuffle reduce. Raw scores to s[b][m][8].
__global__ __launch_bounds__(256) void k_scores(
    const float* __restrict__ q, const float* __restrict__ k,
    const int* __restrict__ e, float* __restrict__ s, int n, int m)
{
    int wave = (int)((blockIdx.x * blockDim.x + threadIdx.x) >> 6);
    int lane = threadIdx.x & 63;
    int j0 = wave * EPW;
    if (j0 >= m) return;

    int e0[EPW], e1[EPW];
    #pragma unroll
    for (int t = 0; t < EPW; ++t) {
        int j = j0 + t;
        int ok = (j < m);
        e0[t] = ok ? e[j]     : 0;
        e1[t] = ok ? e[m + j] : 0;
    }

    float4 qa[B][EPW], kb[B][EPW];
    #pragma unroll
    for (int bb = 0; bb < B; ++bb) {
        #pragma unroll
        for (int t = 0; t < EPW; ++t) {
            qa[bb][t] = ((const float4*)(q + ((size_t)bb * n + e0[t]) * D))[lane];
            kb[bb][t] = ((const float4*)(k + ((size_t)bb * n + e1[t]) * D))[lane];
        }
    }

    #pragma unroll
    for (int bb = 0; bb < B; ++bb) {
        #pragma unroll
        for (int t = 0; t < EPW; ++t) {
            float4 A = qa[bb][t], K4 = kb[bb][t];
            float p = A.x * K4.x + A.y * K4.y + A.z * K4.z + A.w * K4.w;
            p += __shfl_xor(p, 1);
            p += __shfl_xor(p, 2);
            p += __shfl_xor(p, 4);
            if ((lane & 7) == 0 && (j0 + t) < m) {
                int h = lane >> 3;
                s[((size_t)bb * m + (j0 + t)) * NH + h] = p * 0.0625f; // /sqrt(256)
            }
        }
    }
}

// K2: grid-stride max over all scores; one atomicMax per block. (R1 verbatim)
__global__ __launch_bounds__(256) void k_max(
    const float* __restrict__ s, size_t total, unsigned* __restrict__ gmax)
{
    float mx = -INFINITY;
    for (size_t i = blockIdx.x * (size_t)blockDim.x + threadIdx.x; i < total;
         i += (size_t)gridDim.x * blockDim.x)
        mx = fmaxf(mx, s[i]);
    #pragma unroll
    for (int off = 32; off; off >>= 1)
        mx = fmaxf(mx, __shfl_xor(mx, off));
    __shared__ float sm[4];
    int lane = threadIdx.x & 63, w = threadIdx.x >> 6;
    if (lane == 0) sm[w] = mx;
    __syncthreads();
    if (threadIdx.x == 0) {
        float bm = fmaxf(fmaxf(sm[0], sm[1]), fmaxf(sm[2], sm[3]));
        atomicMax(gmax, f2ord(bm));
    }
}

// K3: ex = exp(s - M) in-place; atomicAdd into seg[r[j]][bb][h]. (R1 verbatim)
__global__ __launch_bounds__(256) void k_exp_seg(
    float* __restrict__ s, const int* __restrict__ r,
    const unsigned* __restrict__ gmax, float* __restrict__ seg, int m)
{
    float M = ord2f(*gmax);
    size_t total = (size_t)B * m * NH;
    for (size_t i = blockIdx.x * (size_t)blockDim.x + threadIdx.x; i < total;
         i += (size_t)gridDim.x * blockDim.x) {
        float ex = expf(s[i] - M);
        s[i] = ex;
        size_t bj = i >> 3;               // bb*m + j
        int h  = (int)(i & 7);
        int bb = (bj >= (size_t)m) ? 1 : 0;
        int j  = (int)(bj - (size_t)bb * m);
        atomicAdd(&seg[((size_t)r[j] * B + bb) * NH + h], ex);
    }
}

// K4: out = ex / (seg[r[j]][bb][h] + eps), in-place on d_out. (R1 verbatim)
__global__ __launch_bounds__(256) void k_norm(
    float* __restrict__ s, const int* __restrict__ r,
    const float* __restrict__ seg, int m)
{
    size_t total = (size_t)B * m * NH;
    for (size_t i = blockIdx.x * (size_t)blockDim.x + threadIdx.x; i < total;
         i += (size_t)gridDim.x * blockDim.x) {
        size_t bj = i >> 3;
        int h  = (int)(i & 7);
        int bb = (bj >= (size_t)m) ? 1 : 0;
        int j  = (int)(bj - (size_t)bb * m);
        float denom = seg[((size_t)r[j] * B + bb) * NH + h] + 1e-16f;
        s[i] = s[i] / denom;
    }
}

extern "C" void kernel_launch(void* const* d_in, const int* in_sizes, int n_in,
                              void* d_out, int out_size, void* d_ws, size_t ws_size,
                              hipStream_t stream) {
    const float* q = (const float*)d_in[0];
    const float* k = (const float*)d_in[1];
    const int*   e = (const int*)d_in[2];
    const int*   r = (const int*)d_in[3];
    float* s = (float*)d_out;               // scores -> ex -> out, in place

    int n = in_sizes[0] / (B * D);          // 20000
    int m = in_sizes[3];                    // 320000

    unsigned* gmax = (unsigned*)d_ws;
    float*    seg  = (float*)((char*)d_ws + 16);
    size_t seg_bytes = (size_t)n * B * NH * sizeof(float);

    // zero max slot (ord 0 == very negative float) + seg accumulators
    hipMemsetAsync(d_ws, 0, 16 + seg_bytes, stream);

    size_t total = (size_t)B * m * NH;      // 5.12M

    // K1: EPW edges/wave, 4 waves/block
    int waves  = (m + EPW - 1) / EPW;
    int blocks = (waves + 3) / 4;
    k_scores<<<blocks, 256, 0, stream>>>(q, k, e, s, n, m);
    // K2: global max
    k_max<<<1024, 256, 0, stream>>>(s, total, gmax);
    // K3: exp + segment sum
    k_exp_seg<<<4096, 256, 0, stream>>>(s, r, gmax, seg, m);
    // K4: normalize
    k_norm<<<4096, 256, 0, stream>>>(s, r, seg, m);
}

// Round 4
// 292.970 us; speedup vs baseline: 1.1845x; 1.1635x over previous
//
#include <hip/hip_runtime.h>
#include <hip/hip_bf16.h>
#include <cmath>

#define D 256
#define NH 8
#define B 2
#define EPW 4   // edges per wave

// ---- ordered-uint mapping for float atomicMax ----
__device__ inline unsigned f2ord(float f) {
    unsigned u = __float_as_uint(f);
    return (u & 0x80000000u) ? ~u : (u | 0x80000000u);
}
__device__ inline float ord2f(unsigned u) {
    unsigned b = (u & 0x80000000u) ? (u & 0x7FFFFFFFu) : ~u;
    return __uint_as_float(b);
}
__device__ inline unsigned short f2bf(float f) {
    unsigned u = __float_as_uint(f);
    unsigned r = u + 0x7FFFu + ((u >> 16) & 1u);   // round-to-nearest-even
    return (unsigned short)(r >> 16);
}

// K0: fp32 [bb][node][d] -> packed bf16 [node][bb][d] (1KB per node, both
// batches contiguous). One thread = 4 d-values of q AND k.
__global__ __launch_bounds__(256) void k_conv(
    const float* __restrict__ q, const float* __restrict__ k,
    ushort4* __restrict__ qc, ushort4* __restrict__ kc, int n)
{
    int total = n * B * (D / 4);          // 2.56M quads
    for (int i = blockIdx.x * blockDim.x + threadIdx.x; i < total;
         i += gridDim.x * blockDim.x) {
        int d4  = i & 63;                 // quad within row
        int row = i >> 6;                 // bb*n + node  (source row order)
        int bb  = (row >= n) ? 1 : 0;
        int node = row - bb * n;
        const float4 a = ((const float4*)q)[(size_t)row * 64 + d4];
        const float4 b = ((const float4*)k)[(size_t)row * 64 + d4];
        size_t dst = ((size_t)node * B + bb) * 64 + d4;   // ushort4 units
        qc[dst] = make_ushort4(f2bf(a.x), f2bf(a.y), f2bf(a.z), f2bf(a.w));
        kc[dst] = make_ushort4(f2bf(b.x), f2bf(b.y), f2bf(b.z), f2bf(b.w));
    }
}

// K1 (bf16): one wave = EPW edges. Per edge: ONE uint4 load per array covers
// both batches (lane*16B within the 1KB node row; lanes 0-31 bb=0, 32-63 bb=1;
// 4 lanes per head). xor-reduce over 4 lanes. Raw scores to s[b][m][8].
__global__ __launch_bounds__(256) void k_scores_bf(
    const ushort* __restrict__ qc, const ushort* __restrict__ kc,
    const int* __restrict__ e, float* __restrict__ s, int m)
{
    int wave = (int)((blockIdx.x * blockDim.x + threadIdx.x) >> 6);
    int lane = threadIdx.x & 63;
    int j0 = wave * EPW;
    if (j0 >= m) return;

    int e0[EPW], e1[EPW];
    #pragma unroll
    for (int t = 0; t < EPW; ++t) {
        int j = j0 + t;
        int ok = (j < m);
        e0[t] = ok ? e[j]     : 0;
        e1[t] = ok ? e[m + j] : 0;
    }

    uint4 qa[EPW], kb[EPW];
    #pragma unroll
    for (int t = 0; t < EPW; ++t) {
        qa[t] = ((const uint4*)(qc + (size_t)e0[t] * (B * D)))[lane];
        kb[t] = ((const uint4*)(kc + (size_t)e1[t] * (B * D)))[lane];
    }

    #pragma unroll
    for (int t = 0; t < EPW; ++t) {
        float p = 0.f;
        const unsigned* qw = (const unsigned*)&qa[t];
        const unsigned* kw = (const unsigned*)&kb[t];
        #pragma unroll
        for (int w = 0; w < 4; ++w) {
            float ql = __uint_as_float(qw[w] << 16);
            float qh = __uint_as_float(qw[w] & 0xFFFF0000u);
            float kl = __uint_as_float(kw[w] << 16);
            float kh = __uint_as_float(kw[w] & 0xFFFF0000u);
            p = fmaf(ql, kl, p);
            p = fmaf(qh, kh, p);
        }
        p += __shfl_xor(p, 1);
        p += __shfl_xor(p, 2);
        if ((lane & 3) == 0 && (j0 + t) < m) {
            int bb = lane >> 5;
            int h  = (lane >> 2) & 7;
            s[((size_t)bb * m + (j0 + t)) * NH + h] = p * 0.0625f;
        }
    }
}

// K1 (fp32 fallback, R3 verbatim) — used only if ws_size too small.
__global__ __launch_bounds__(256) void k_scores_f32(
    const float* __restrict__ q, const float* __restrict__ k,
    const int* __restrict__ e, float* __restrict__ s, int n, int m)
{
    int wave = (int)((blockIdx.x * blockDim.x + threadIdx.x) >> 6);
    int lane = threadIdx.x & 63;
    int j0 = wave * EPW;
    if (j0 >= m) return;
    int e0[EPW], e1[EPW];
    #pragma unroll
    for (int t = 0; t < EPW; ++t) {
        int j = j0 + t; int ok = (j < m);
        e0[t] = ok ? e[j] : 0; e1[t] = ok ? e[m + j] : 0;
    }
    float4 qa[B][EPW], kb[B][EPW];
    #pragma unroll
    for (int bb = 0; bb < B; ++bb)
        #pragma unroll
        for (int t = 0; t < EPW; ++t) {
            qa[bb][t] = ((const float4*)(q + ((size_t)bb * n + e0[t]) * D))[lane];
            kb[bb][t] = ((const float4*)(k + ((size_t)bb * n + e1[t]) * D))[lane];
        }
    #pragma unroll
    for (int bb = 0; bb < B; ++bb)
        #pragma unroll
        for (int t = 0; t < EPW; ++t) {
            float4 A = qa[bb][t], K4 = kb[bb][t];
            float p = A.x * K4.x + A.y * K4.y + A.z * K4.z + A.w * K4.w;
            p += __shfl_xor(p, 1); p += __shfl_xor(p, 2); p += __shfl_xor(p, 4);
            if ((lane & 7) == 0 && (j0 + t) < m) {
                int h = lane >> 3;
                s[((size_t)bb * m + (j0 + t)) * NH + h] = p * 0.0625f;
            }
        }
}

// K2: grid-stride max; one atomicMax per block. (R3 verbatim)
__global__ __launch_bounds__(256) void k_max(
    const float* __restrict__ s, size_t total, unsigned* __restrict__ gmax)
{
    float mx = -INFINITY;
    for (size_t i = blockIdx.x * (size_t)blockDim.x + threadIdx.x; i < total;
         i += (size_t)gridDim.x * blockDim.x)
        mx = fmaxf(mx, s[i]);
    #pragma unroll
    for (int off = 32; off; off >>= 1)
        mx = fmaxf(mx, __shfl_xor(mx, off));
    __shared__ float sm[4];
    int lane = threadIdx.x & 63, w = threadIdx.x >> 6;
    if (lane == 0) sm[w] = mx;
    __syncthreads();
    if (threadIdx.x == 0) {
        float bm = fmaxf(fmaxf(sm[0], sm[1]), fmaxf(sm[2], sm[3]));
        atomicMax(gmax, f2ord(bm));
    }
}

// K3: ex = exp(s - M) in-place; atomicAdd into seg. (R3 verbatim)
__global__ __launch_bounds__(256) void k_exp_seg(
    float* __restrict__ s, const int* __restrict__ r,
    const unsigned* __restrict__ gmax, float* __restrict__ seg, int m)
{
    float M = ord2f(*gmax);
    size_t total = (size_t)B * m * NH;
    for (size_t i = blockIdx.x * (size_t)blockDim.x + threadIdx.x; i < total;
         i += (size_t)gridDim.x * blockDim.x) {
        float ex = expf(s[i] - M);
        s[i] = ex;
        size_t bj = i >> 3;
        int h  = (int)(i & 7);
        int bb = (bj >= (size_t)m) ? 1 : 0;
        int j  = (int)(bj - (size_t)bb * m);
        atomicAdd(&seg[((size_t)r[j] * B + bb) * NH + h], ex);
    }
}

// K4: normalize in place. (R3 verbatim)
__global__ __launch_bounds__(256) void k_norm(
    float* __restrict__ s, const int* __restrict__ r,
    const float* __restrict__ seg, int m)
{
    size_t total = (size_t)B * m * NH;
    for (size_t i = blockIdx.x * (size_t)blockDim.x + threadIdx.x; i < total;
         i += (size_t)gridDim.x * blockDim.x) {
        size_t bj = i >> 3;
        int h  = (int)(i & 7);
        int bb = (bj >= (size_t)m) ? 1 : 0;
        int j  = (int)(bj - (size_t)bb * m);
        float denom = seg[((size_t)r[j] * B + bb) * NH + h] + 1e-16f;
        s[i] = s[i] / denom;
    }
}

extern "C" void kernel_launch(void* const* d_in, const int* in_sizes, int n_in,
                              void* d_out, int out_size, void* d_ws, size_t ws_size,
                              hipStream_t stream) {
    const float* q = (const float*)d_in[0];
    const float* k = (const float*)d_in[1];
    const int*   e = (const int*)d_in[2];
    const int*   r = (const int*)d_in[3];
    float* s = (float*)d_out;

    int n = in_sizes[0] / (B * D);          // 20000
    int m = in_sizes[3];                    // 320000

    // ws layout: gmax @0 (16B) | seg @16 | qc | kc
    size_t seg_bytes = (size_t)n * B * NH * sizeof(float);       // 1.28 MB
    size_t row_bytes = (size_t)n * B * D * sizeof(unsigned short); // 20.48 MB
    unsigned* gmax = (unsigned*)d_ws;
    float*    seg  = (float*)((char*)d_ws + 16);
    ushort*   qc   = (ushort*)((char*)d_ws + 16 + seg_bytes);
    ushort*   kc   = (ushort*)((char*)d_ws + 16 + seg_bytes + row_bytes);
    bool use_bf16 = ws_size >= (16 + seg_bytes + 2 * row_bytes);

    hipMemsetAsync(d_ws, 0, 16 + seg_bytes, stream);

    size_t total = (size_t)B * m * NH;
    int waves  = (m + EPW - 1) / EPW;
    int blocks = (waves + 3) / 4;

    if (use_bf16) {
        k_conv<<<4096, 256, 0, stream>>>(q, k, (ushort4*)qc, (ushort4*)kc, n);
        k_scores_bf<<<blocks, 256, 0, stream>>>(qc, kc, e, s, m);
    } else {
        k_scores_f32<<<blocks, 256, 0, stream>>>(q, k, e, s, n, m);
    }
    k_max<<<1024, 256, 0, stream>>>(s, total, gmax);
    k_exp_seg<<<4096, 256, 0, stream>>>(s, r, gmax, seg, m);
    k_norm<<<4096, 256, 0, stream>>>(s, r, seg, m);
}